// Round 1
// baseline (1519.869 us; speedup 1.0000x reference)
//
#include <hip/hip_runtime.h>
#include <hip/hip_bf16.h>

#define N_NODES 50000
#define N_EDGES 500000
#define F_DIM   128
#define N_REL   8
#define N_LAYERS 2
#define NEG_SLOPE 0.2f

// ---------------- helpers ----------------

__device__ inline void atomAddF(float* p, float v) {
#if defined(__HIP_DEVICE_COMPILE__)
    unsafeAtomicAdd(p, v);   // global_atomic_add_f32 (HW fp atomic)
#else
    atomicAdd(p, v);
#endif
}

// ordered-uint encoding so atomicMax(uint) == float max
__device__ inline unsigned encF(float f) {
    unsigned u = __float_as_uint(f);
    return (u & 0x80000000u) ? ~u : (u | 0x80000000u);
}
__device__ inline float decF(unsigned u) {
    return (u & 0x80000000u) ? __uint_as_float(u & 0x7fffffffu)
                             : __uint_as_float(~u);
}

// storage-type abstraction: xw kept as fp32 (preferred) or bf16 (small-ws fallback)
__device__ inline float2 ld2(const float* p) { return *(const float2*)p; }
__device__ inline float2 ld2(const __hip_bfloat16* p) {
    unsigned u = *(const unsigned*)p;
    return make_float2(__uint_as_float(u << 16), __uint_as_float(u & 0xffff0000u));
}
__device__ inline unsigned short f2bf(float f) {
    __hip_bfloat16 b = __float2bfloat16(f);
    return *reinterpret_cast<unsigned short*>(&b);
}
__device__ inline void store_row8(float* dst, const float* a) {
    *(float4*)dst       = make_float4(a[0], a[1], a[2], a[3]);
    *(float4*)(dst + 4) = make_float4(a[4], a[5], a[6], a[7]);
}
__device__ inline void store_row8(__hip_bfloat16* dst, const float* a) {
    alignas(16) unsigned short hs[8];
#pragma unroll
    for (int i = 0; i < 8; ++i) hs[i] = f2bf(a[i]);
    *(uint4*)dst = *(const uint4*)hs;
}

// ---------------- kernels ----------------

// xw[r,n,g] = sum_f H[n,f] * W[r,f,g].   H fp32 [N,128], W fp32 [R,128,128].
// Tile: BM=128 rows x BN=128 cols (full), BK=16. 256 threads, 8x8 micro-tile.
#define BM 128
#define BK 16
template <typename T>
__global__ __launch_bounds__(256) void gemm_xw(const float* __restrict__ H,
                                               const float* __restrict__ Wl,
                                               T* __restrict__ xw) {
    const int r  = blockIdx.y;
    const int m0 = blockIdx.x * BM;
    const float* B = Wl + r * F_DIM * F_DIM;

    __shared__ float As[BK][BM];   // [k][m]
    __shared__ float Bs[BK][F_DIM];

    const int tid = threadIdx.x;
    const int tx = tid & 15;   // col group: cols tx*8 .. +7
    const int ty = tid >> 4;   // row group: rows ty*8 .. +7

    float acc[8][8] = {};

    for (int k0 = 0; k0 < F_DIM; k0 += BK) {
        // A tile: 128 rows x 16 k = 512 float4, 2 per thread
#pragma unroll
        for (int i = 0; i < 2; ++i) {
            int f  = tid + i * 256;
            int m  = f >> 2;
            int kq = f & 3;
            float4 v = make_float4(0.f, 0.f, 0.f, 0.f);
            int gm = m0 + m;
            if (gm < N_NODES) v = *(const float4*)(H + (size_t)gm * F_DIM + k0 + kq * 4);
            As[kq * 4 + 0][m] = v.x;
            As[kq * 4 + 1][m] = v.y;
            As[kq * 4 + 2][m] = v.z;
            As[kq * 4 + 3][m] = v.w;
        }
        // B tile: 16 x 128 = 512 float4, 2 per thread
#pragma unroll
        for (int i = 0; i < 2; ++i) {
            int f  = tid + i * 256;
            int kk = f >> 5;
            int g4 = f & 31;
            *(float4*)(&Bs[kk][g4 * 4]) = *(const float4*)(B + (k0 + kk) * F_DIM + g4 * 4);
        }
        __syncthreads();
#pragma unroll
        for (int kk = 0; kk < BK; ++kk) {
            float a[8], b[8];
            *(float4*)(a)     = *(const float4*)(&As[kk][ty * 8]);
            *(float4*)(a + 4) = *(const float4*)(&As[kk][ty * 8 + 4]);
            *(float4*)(b)     = *(const float4*)(&Bs[kk][tx * 8]);
            *(float4*)(b + 4) = *(const float4*)(&Bs[kk][tx * 8 + 4]);
#pragma unroll
            for (int i = 0; i < 8; ++i)
#pragma unroll
                for (int j = 0; j < 8; ++j)
                    acc[i][j] = fmaf(a[i], b[j], acc[i][j]);
        }
        __syncthreads();
    }
    // epilogue
#pragma unroll
    for (int i = 0; i < 8; ++i) {
        int gm = m0 + ty * 8 + i;
        if (gm >= N_NODES) continue;
        T* dst = xw + ((size_t)r * N_NODES + gm) * F_DIM + tx * 8;
        store_row8(dst, acc[i]);
    }
}

// a_q[row] = xw[row,:].q ; a_k[row] = xw[row,:].k   (row = r*N + n). 1 wave/row.
template <typename T>
__global__ __launch_bounds__(256) void qk_kernel(const T* __restrict__ xw,
                                                 const float* __restrict__ q,
                                                 const float* __restrict__ k,
                                                 float* __restrict__ a_q,
                                                 float* __restrict__ a_k) {
    const int lane = threadIdx.x & 63;
    const int wave = threadIdx.x >> 6;
    const int row  = blockIdx.x * 4 + wave;
    if (row >= N_REL * N_NODES) return;
    float2 v  = ld2(xw + (size_t)row * F_DIM + lane * 2);
    float2 qq = *(const float2*)(q + lane * 2);
    float2 kk = *(const float2*)(k + lane * 2);
    float pq = v.x * qq.x + v.y * qq.y;
    float pk = v.x * kk.x + v.y * kk.y;
#pragma unroll
    for (int off = 32; off > 0; off >>= 1) {
        pq += __shfl_down(pq, off);
        pk += __shfl_down(pk, off);
    }
    if (lane == 0) { a_q[row] = pq; a_k[row] = pk; }
}

// logits + running segment max (per dst)
__global__ __launch_bounds__(256) void logits_kernel(const int* __restrict__ srcp,
                                                     const int* __restrict__ dstp,
                                                     const int* __restrict__ etp,
                                                     const float* __restrict__ a_q,
                                                     const float* __restrict__ a_k,
                                                     float* __restrict__ elog,
                                                     unsigned* __restrict__ m_u) {
    int e = blockIdx.x * 256 + threadIdx.x;
    if (e >= N_EDGES) return;
    int s = srcp[e], d = dstp[e], t = etp[e];
    float l = a_q[(size_t)t * N_NODES + d] + a_k[(size_t)t * N_NODES + s];
    l = (l > 0.f) ? l : NEG_SLOPE * l;
    elog[e] = l;
    atomicMax(m_u + d, encF(l));
}

// e = exp(l - m[dst]); denom[dst] += e
__global__ __launch_bounds__(256) void exp_kernel(const int* __restrict__ dstp,
                                                  float* __restrict__ elog,
                                                  const unsigned* __restrict__ m_u,
                                                  float* __restrict__ denom) {
    int e = blockIdx.x * 256 + threadIdx.x;
    if (e >= N_EDGES) return;
    int d = dstp[e];
    float ex = expf(elog[e] - decF(m_u[d]));
    elog[e] = ex;
    atomAddF(denom + d, ex);
}

// h_next[dst] += alpha * xw[et, src].  1 wave per edge, 2 feats/lane.
template <typename T>
__global__ __launch_bounds__(256) void aggregate_kernel(const T* __restrict__ xw,
                                                        const float* __restrict__ elog,
                                                        const float* __restrict__ denom,
                                                        const int* __restrict__ srcp,
                                                        const int* __restrict__ dstp,
                                                        const int* __restrict__ etp,
                                                        float* __restrict__ h_next) {
    const int lane = threadIdx.x & 63;
    const int wave = threadIdx.x >> 6;
    const int e = blockIdx.x * 4 + wave;
    if (e >= N_EDGES) return;
    int s = srcp[e], d = dstp[e], t = etp[e];
    float alpha = elog[e] / (denom[d] + 1e-16f);
    float2 v = ld2(xw + ((size_t)t * N_NODES + s) * F_DIM + lane * 2);
    float* outp = h_next + (size_t)d * F_DIM + lane * 2;
    atomAddF(outp,     alpha * v.x);
    atomAddF(outp + 1, alpha * v.y);
}

// h = relu(h + bias)
__global__ __launch_bounds__(256) void bias_relu_kernel(float* __restrict__ h,
                                                        const float* __restrict__ b) {
    int idx = blockIdx.x * 256 + threadIdx.x;              // float4 index
    if (idx >= N_NODES * F_DIM / 4) return;
    float4 v  = ((float4*)h)[idx];
    float4 bb = ((const float4*)b)[idx & 31];
    v.x = fmaxf(v.x + bb.x, 0.f);
    v.y = fmaxf(v.y + bb.y, 0.f);
    v.z = fmaxf(v.z + bb.z, 0.f);
    v.w = fmaxf(v.w + bb.w, 0.f);
    ((float4*)h)[idx] = v;
}

// ---------------- driver ----------------

template <typename T>
static void run_pipeline(const float* x, const float* W, const float* att_q,
                         const float* att_k, const float* bias,
                         const int* srcp, const int* dstp, const int* etp,
                         float* out, char* ws, hipStream_t stream) {
    size_t off = 0;
    auto alloc = [&](size_t bytes) {
        void* p = ws + off;
        off = (off + bytes + 511) & ~(size_t)511;
        return p;
    };
    T* xw         = (T*)alloc((size_t)N_REL * N_NODES * F_DIM * sizeof(T));
    float* a_q    = (float*)alloc((size_t)N_REL * N_NODES * sizeof(float));
    float* a_k    = (float*)alloc((size_t)N_REL * N_NODES * sizeof(float));
    unsigned* m_u = (unsigned*)alloc((size_t)N_NODES * sizeof(unsigned));
    float* denom  = (float*)alloc((size_t)N_NODES * sizeof(float));
    float* elog   = (float*)alloc((size_t)N_EDGES * sizeof(float));

    const int grid_m = (N_NODES + BM - 1) / BM;  // 391
    for (int l = 0; l < N_LAYERS; ++l) {
        const float* H = (l == 0) ? x : out;
        gemm_xw<T><<<dim3(grid_m, N_REL), 256, 0, stream>>>(
            H, W + (size_t)l * N_REL * F_DIM * F_DIM, xw);
        qk_kernel<T><<<(N_REL * N_NODES + 3) / 4, 256, 0, stream>>>(
            xw, att_q + l * F_DIM, att_k + l * F_DIM, a_q, a_k);
        hipMemsetAsync(m_u, 0, (size_t)N_NODES * 4, stream);
        hipMemsetAsync(denom, 0, (size_t)N_NODES * 4, stream);
        logits_kernel<<<(N_EDGES + 255) / 256, 256, 0, stream>>>(
            srcp, dstp, etp, a_q, a_k, elog, m_u);
        exp_kernel<<<(N_EDGES + 255) / 256, 256, 0, stream>>>(
            dstp, elog, m_u, denom);
        hipMemsetAsync(out, 0, (size_t)N_NODES * F_DIM * 4, stream);
        aggregate_kernel<T><<<(N_EDGES + 3) / 4, 256, 0, stream>>>(
            xw, elog, denom, srcp, dstp, etp, out);
        bias_relu_kernel<<<(N_NODES * F_DIM / 4 + 255) / 256, 256, 0, stream>>>(
            out, bias + l * F_DIM);
    }
}

extern "C" void kernel_launch(void* const* d_in, const int* in_sizes, int n_in,
                              void* d_out, int out_size, void* d_ws, size_t ws_size,
                              hipStream_t stream) {
    const float* x     = (const float*)d_in[0];
    const float* W     = (const float*)d_in[1];
    const float* att_q = (const float*)d_in[2];
    const float* att_k = (const float*)d_in[3];
    const float* bias  = (const float*)d_in[4];
    const int* ei      = (const int*)d_in[5];
    const int* etp     = (const int*)d_in[6];
    const int* srcp = ei;
    const int* dstp = ei + N_EDGES;
    float* out = (float*)d_out;
    char* ws   = (char*)d_ws;

    // fp32 xw needs ~210 MB of ws; fall back to bf16 storage (~108 MB) if short.
    size_t need_f32 = (size_t)N_REL * N_NODES * F_DIM * 4 + (size_t)16 * 1024 * 1024;
    if (ws_size >= need_f32) {
        run_pipeline<float>(x, W, att_q, att_k, bias, srcp, dstp, etp, out, ws, stream);
    } else {
        run_pipeline<__hip_bfloat16>(x, W, att_q, att_k, bias, srcp, dstp, etp, out, ws, stream);
    }
}

// Round 2
// 617.492 us; speedup vs baseline: 2.4614x; 2.4614x over previous
//
#include <hip/hip_runtime.h>
#include <hip/hip_bf16.h>

#define N_NODES 50000
#define N_EDGES 500000
#define F_DIM   128
#define N_REL   8
#define N_LAYERS 2
#define NEG_SLOPE 0.2f

#define NBLK_N ((N_NODES + 255) / 256)   // 196 blocks over nodes

// ---------------- helpers ----------------

__device__ inline float2 ld2(const float* p) { return *(const float2*)p; }
__device__ inline float2 ld2(const __hip_bfloat16* p) {
    unsigned u = *(const unsigned*)p;
    return make_float2(__uint_as_float(u << 16), __uint_as_float(u & 0xffff0000u));
}
__device__ inline unsigned short f2bf(float f) {
    __hip_bfloat16 b = __float2bfloat16(f);
    return *reinterpret_cast<unsigned short*>(&b);
}
__device__ inline void store_row8(float* dst, const float* a) {
    *(float4*)dst       = make_float4(a[0], a[1], a[2], a[3]);
    *(float4*)(dst + 4) = make_float4(a[4], a[5], a[6], a[7]);
}
__device__ inline void store_row8(__hip_bfloat16* dst, const float* a) {
    alignas(16) unsigned short hs[8];
#pragma unroll
    for (int i = 0; i < 8; ++i) hs[i] = f2bf(a[i]);
    *(uint4*)dst = *(const uint4*)hs;
}
__device__ inline float lrelu(float l) { return (l > 0.f) ? l : NEG_SLOPE * l; }

// ---------------- GEMM (+fused q/k dots) ----------------
// xw[r,n,g] = sum_f H[n,f] * W[r,f,g];  a_q[r,n] = xw[r,n,:].q ; a_k likewise.
#define BM 128
#define BK 16
template <typename T>
__global__ __launch_bounds__(256) void gemm_xw(const float* __restrict__ H,
                                               const float* __restrict__ Wl,
                                               const float* __restrict__ qv_g,
                                               const float* __restrict__ kv_g,
                                               T* __restrict__ xw,
                                               float* __restrict__ a_q,
                                               float* __restrict__ a_k) {
    const int r  = blockIdx.y;
    const int m0 = blockIdx.x * BM;
    const float* B = Wl + r * F_DIM * F_DIM;

    __shared__ float As[BK][BM];   // [k][m]
    __shared__ float Bs[BK][F_DIM];

    const int tid = threadIdx.x;
    const int tx = tid & 15;   // cols tx*8 .. +7
    const int ty = tid >> 4;   // rows ty*8 .. +7

    float acc[8][8] = {};

    for (int k0 = 0; k0 < F_DIM; k0 += BK) {
#pragma unroll
        for (int i = 0; i < 2; ++i) {
            int f  = tid + i * 256;
            int m  = f >> 2;
            int kq = f & 3;
            float4 v = make_float4(0.f, 0.f, 0.f, 0.f);
            int gm = m0 + m;
            if (gm < N_NODES) v = *(const float4*)(H + (size_t)gm * F_DIM + k0 + kq * 4);
            As[kq * 4 + 0][m] = v.x;
            As[kq * 4 + 1][m] = v.y;
            As[kq * 4 + 2][m] = v.z;
            As[kq * 4 + 3][m] = v.w;
        }
#pragma unroll
        for (int i = 0; i < 2; ++i) {
            int f  = tid + i * 256;
            int kk = f >> 5;
            int g4 = f & 31;
            *(float4*)(&Bs[kk][g4 * 4]) = *(const float4*)(B + (k0 + kk) * F_DIM + g4 * 4);
        }
        __syncthreads();
#pragma unroll
        for (int kk = 0; kk < BK; ++kk) {
            float a[8], b[8];
            *(float4*)(a)     = *(const float4*)(&As[kk][ty * 8]);
            *(float4*)(a + 4) = *(const float4*)(&As[kk][ty * 8 + 4]);
            *(float4*)(b)     = *(const float4*)(&Bs[kk][tx * 8]);
            *(float4*)(b + 4) = *(const float4*)(&Bs[kk][tx * 8 + 4]);
#pragma unroll
            for (int i = 0; i < 8; ++i)
#pragma unroll
                for (int j = 0; j < 8; ++j)
                    acc[i][j] = fmaf(a[i], b[j], acc[i][j]);
        }
        __syncthreads();
    }

    // q/k vectors for this thread's 8 columns
    float qv[8], kv[8];
    *(float4*)(qv)     = *(const float4*)(qv_g + tx * 8);
    *(float4*)(qv + 4) = *(const float4*)(qv_g + tx * 8 + 4);
    *(float4*)(kv)     = *(const float4*)(kv_g + tx * 8);
    *(float4*)(kv + 4) = *(const float4*)(kv_g + tx * 8 + 4);

#pragma unroll
    for (int i = 0; i < 8; ++i) {
        int gm = m0 + ty * 8 + i;
        bool ok = (gm < N_NODES);
        if (ok) {
            T* dst = xw + ((size_t)r * N_NODES + gm) * F_DIM + tx * 8;
            store_row8(dst, acc[i]);
        }
        // fused q/k dot: partial over this thread's 8 cols, reduce across tx
        float pq = 0.f, pk = 0.f;
#pragma unroll
        for (int j = 0; j < 8; ++j) {
            pq = fmaf(acc[i][j], qv[j], pq);
            pk = fmaf(acc[i][j], kv[j], pk);
        }
#pragma unroll
        for (int m = 1; m <= 8; m <<= 1) {
            pq += __shfl_xor(pq, m);
            pk += __shfl_xor(pk, m);
        }
        if (ok && tx == 0) {
            a_q[(size_t)r * N_NODES + gm] = pq;
            a_k[(size_t)r * N_NODES + gm] = pk;
        }
    }
}

// ---------------- CSR build (once per call; edge list is layer-invariant) ----

__global__ __launch_bounds__(256) void count_kernel(const int* __restrict__ dstp,
                                                    int* __restrict__ cnt) {
    int e = blockIdx.x * 256 + threadIdx.x;
    if (e < N_EDGES) atomicAdd(cnt + dstp[e], 1);
}

// per-block sums of cnt
__global__ __launch_bounds__(256) void block_sum_kernel(const int* __restrict__ cnt,
                                                        int* __restrict__ partial) {
    __shared__ int s[256];
    int idx = blockIdx.x * 256 + threadIdx.x;
    int v = (idx < N_NODES) ? cnt[idx] : 0;
    s[threadIdx.x] = v;
    __syncthreads();
    for (int off = 128; off > 0; off >>= 1) {
        if (threadIdx.x < off) s[threadIdx.x] += s[threadIdx.x + off];
        __syncthreads();
    }
    if (threadIdx.x == 0) partial[blockIdx.x] = s[0];
}

// exclusive scan of the (<=256) partials, single block
__global__ __launch_bounds__(256) void scan_partials_kernel(int* __restrict__ partial,
                                                            int* __restrict__ row_ptr) {
    __shared__ int s[256];
    int t = threadIdx.x;
    int v = (t < NBLK_N) ? partial[t] : 0;
    s[t] = v;
    __syncthreads();
#pragma unroll
    for (int off = 1; off < 256; off <<= 1) {
        int x = (t >= off) ? s[t - off] : 0;
        __syncthreads();
        s[t] += x;
        __syncthreads();
    }
    if (t < NBLK_N) partial[t] = s[t] - v;   // exclusive
    if (t == 0) row_ptr[N_NODES] = N_EDGES;
}

// per-block exclusive scan + offset -> row_ptr
__global__ __launch_bounds__(256) void scan_block_kernel(const int* __restrict__ cnt,
                                                         const int* __restrict__ partial,
                                                         int* __restrict__ row_ptr) {
    __shared__ int s[256];
    int t = threadIdx.x;
    int idx = blockIdx.x * 256 + t;
    int v = (idx < N_NODES) ? cnt[idx] : 0;
    s[t] = v;
    __syncthreads();
#pragma unroll
    for (int off = 1; off < 256; off <<= 1) {
        int x = (t >= off) ? s[t - off] : 0;
        __syncthreads();
        s[t] += x;
        __syncthreads();
    }
    if (idx < N_NODES) row_ptr[idx] = partial[blockIdx.x] + s[t] - v;
}

__global__ __launch_bounds__(256) void scatter_kernel(const int* __restrict__ srcp,
                                                      const int* __restrict__ dstp,
                                                      const int* __restrict__ etp,
                                                      const int* __restrict__ row_ptr,
                                                      int* __restrict__ cursor,
                                                      unsigned* __restrict__ sorted) {
    int e = blockIdx.x * 256 + threadIdx.x;
    if (e >= N_EDGES) return;
    int d = dstp[e];
    int pos = atomicAdd(cursor + d, 1);
    sorted[row_ptr[d] + pos] = (unsigned)srcp[e] | ((unsigned)etp[e] << 16);
}

// ---------------- fused softmax + aggregate + bias + relu ----------------
// one wave per dst node; 2 features per lane.
template <typename T>
__global__ __launch_bounds__(256) void agg_fused(const T* __restrict__ xw,
                                                 const float* __restrict__ a_q,
                                                 const float* __restrict__ a_k,
                                                 const int* __restrict__ row_ptr,
                                                 const unsigned* __restrict__ sorted,
                                                 const float* __restrict__ bias,
                                                 float* __restrict__ out) {
    const int lane = threadIdx.x & 63;
    const int wave = threadIdx.x >> 6;
    const int d = blockIdx.x * 4 + wave;
    if (d >= N_NODES) return;
    const int beg = row_ptr[d], end = row_ptr[d + 1];

    // phase 1: segment max (lanes strided over edges)
    float m = -3.4e38f;
    for (int i = beg + lane; i < end; i += 64) {
        unsigned p = sorted[i];
        int s = p & 0xffff, t = p >> 16;
        float l = lrelu(a_q[t * N_NODES + d] + a_k[t * N_NODES + s]);
        m = fmaxf(m, l);
    }
#pragma unroll
    for (int off = 32; off > 0; off >>= 1) m = fmaxf(m, __shfl_xor(m, off));

    // phase 2: exp-sum
    float dsum = 0.f;
    for (int i = beg + lane; i < end; i += 64) {
        unsigned p = sorted[i];
        int s = p & 0xffff, t = p >> 16;
        float l = lrelu(a_q[t * N_NODES + d] + a_k[t * N_NODES + s]);
        dsum += __expf(l - m);
    }
#pragma unroll
    for (int off = 32; off > 0; off >>= 1) dsum += __shfl_xor(dsum, off);
    const float inv = 1.f / (dsum + 1e-16f);

    // phase 3: weighted accumulation, features across lanes
    float2 acc = *(const float2*)(bias + lane * 2);
    for (int i = beg; i < end; ++i) {
        unsigned p = sorted[i];
        int s = p & 0xffff, t = p >> 16;
        float l = lrelu(a_q[t * N_NODES + d] + a_k[t * N_NODES + s]);
        float alpha = __expf(l - m) * inv;
        float2 v = ld2(xw + ((size_t)t * N_NODES + s) * F_DIM + lane * 2);
        acc.x = fmaf(alpha, v.x, acc.x);
        acc.y = fmaf(alpha, v.y, acc.y);
    }
    acc.x = fmaxf(acc.x, 0.f);
    acc.y = fmaxf(acc.y, 0.f);
    *(float2*)(out + (size_t)d * F_DIM + lane * 2) = acc;
}

// ---------------- driver ----------------

template <typename T>
static void run_pipeline(const float* x, const float* W, const float* att_q,
                         const float* att_k, const float* bias,
                         const int* srcp, const int* dstp, const int* etp,
                         float* out, char* ws, hipStream_t stream) {
    size_t off = 0;
    auto alloc = [&](size_t bytes) {
        void* p = ws + off;
        off = (off + bytes + 511) & ~(size_t)511;
        return p;
    };
    T* xw            = (T*)alloc((size_t)N_REL * N_NODES * F_DIM * sizeof(T));
    float* a_q       = (float*)alloc((size_t)N_REL * N_NODES * sizeof(float));
    float* a_k       = (float*)alloc((size_t)N_REL * N_NODES * sizeof(float));
    int* cnt         = (int*)alloc((size_t)N_NODES * sizeof(int));
    int* row_ptr     = (int*)alloc(((size_t)N_NODES + 1) * sizeof(int));
    int* partial     = (int*)alloc(256 * sizeof(int));
    unsigned* sorted = (unsigned*)alloc((size_t)N_EDGES * sizeof(unsigned));

    // --- CSR build (edge structure is identical for both layers) ---
    hipMemsetAsync(cnt, 0, (size_t)N_NODES * 4, stream);
    count_kernel<<<(N_EDGES + 255) / 256, 256, 0, stream>>>(dstp, cnt);
    block_sum_kernel<<<NBLK_N, 256, 0, stream>>>(cnt, partial);
    scan_partials_kernel<<<1, 256, 0, stream>>>(partial, row_ptr);
    scan_block_kernel<<<NBLK_N, 256, 0, stream>>>(cnt, partial, row_ptr);
    hipMemsetAsync(cnt, 0, (size_t)N_NODES * 4, stream);   // reuse as cursor
    scatter_kernel<<<(N_EDGES + 255) / 256, 256, 0, stream>>>(
        srcp, dstp, etp, row_ptr, cnt, sorted);

    const int grid_m = (N_NODES + BM - 1) / BM;  // 391
    for (int l = 0; l < N_LAYERS; ++l) {
        const float* H = (l == 0) ? x : out;
        gemm_xw<T><<<dim3(grid_m, N_REL), 256, 0, stream>>>(
            H, W + (size_t)l * N_REL * F_DIM * F_DIM,
            att_q + l * F_DIM, att_k + l * F_DIM, xw, a_q, a_k);
        agg_fused<T><<<(N_NODES + 3) / 4, 256, 0, stream>>>(
            xw, a_q, a_k, row_ptr, sorted, bias + l * F_DIM, out);
    }
}

extern "C" void kernel_launch(void* const* d_in, const int* in_sizes, int n_in,
                              void* d_out, int out_size, void* d_ws, size_t ws_size,
                              hipStream_t stream) {
    const float* x     = (const float*)d_in[0];
    const float* W     = (const float*)d_in[1];
    const float* att_q = (const float*)d_in[2];
    const float* att_k = (const float*)d_in[3];
    const float* bias  = (const float*)d_in[4];
    const int* ei      = (const int*)d_in[5];
    const int* etp     = (const int*)d_in[6];
    const int* srcp = ei;
    const int* dstp = ei + N_EDGES;
    float* out = (float*)d_out;
    char* ws   = (char*)d_ws;

    size_t need_f32 = (size_t)N_REL * N_NODES * F_DIM * 4 + (size_t)16 * 1024 * 1024;
    if (ws_size >= need_f32) {
        run_pipeline<float>(x, W, att_q, att_k, bias, srcp, dstp, etp, out, ws, stream);
    } else {
        run_pipeline<__hip_bfloat16>(x, W, att_q, att_k, bias, srcp, dstp, etp, out, ws, stream);
    }
}